// Round 1
// baseline (601.073 us; speedup 1.0000x reference)
//
#include <hip/hip_runtime.h>
#include <stdint.h>

typedef short bf16x8 __attribute__((ext_vector_type(8)));
typedef short bf16x4 __attribute__((ext_vector_type(4)));
typedef float f32x4 __attribute__((ext_vector_type(4)));

__device__ __forceinline__ short f2bf(float f) {
  union { float f; uint32_t u; } v; v.f = f;
  uint32_t r = (v.u + 0x7FFFu + ((v.u >> 16) & 1u)) >> 16;
  return (short)(uint16_t)r;
}

// ---------------- elementwise f32 -> bf16 ----------------
__global__ __launch_bounds__(256) void k_convert(const float* __restrict__ in,
                                                 short* __restrict__ out, int n) {
  int i = (blockIdx.x * 256 + threadIdx.x) * 4;
  if (i >= n) return;
  float4 v = *reinterpret_cast<const float4*>(in + i);
  bf16x4 o; o[0] = f2bf(v.x); o[1] = f2bf(v.y); o[2] = f2bf(v.z); o[3] = f2bf(v.w);
  *reinterpret_cast<bf16x4*>(out + i) = o;
}

// ---------------- transpose + convert: out[C][R] = bf16(in[R][C]) ----------------
__global__ __launch_bounds__(256) void k_transpose_cvt(const float* __restrict__ in,
                                                       short* __restrict__ out,
                                                       int R, int C) {
  __shared__ float tile[32][33];
  int r0 = blockIdx.y * 32, c0 = blockIdx.x * 32;
  int tx = threadIdx.x & 31, ty = threadIdx.x >> 5;
#pragma unroll
  for (int j = 0; j < 4; ++j)
    tile[ty + j * 8][tx] = in[(size_t)(r0 + ty + j * 8) * C + c0 + tx];
  __syncthreads();
#pragma unroll
  for (int j = 0; j < 4; ++j)
    out[(size_t)(c0 + ty + j * 8) * R + r0 + tx] = f2bf(tile[tx][ty + j * 8]);
}

// ---------------- GEMM1: qkv = x @ W_attn + b ----------------
// A: xb (16384x1024 bf16), BT: WaT (3072x1024 bf16), C: qkv (16384x3072 bf16)
__global__ __launch_bounds__(256) void k_gemm_qkv(const short* __restrict__ A,
                                                  const short* __restrict__ BT,
                                                  const float* __restrict__ bias,
                                                  short* __restrict__ C) {
  __shared__ short As[128][40];
  __shared__ short Bs[128][40];
  const int tid = threadIdx.x, lane = tid & 63, w = tid >> 6;
  const int wm = w >> 1, wn = w & 1;
  const int r16 = lane & 15, g4 = lane >> 4;
  const int m0 = blockIdx.x * 128, n0 = blockIdx.y * 128;
  f32x4 acc[4][4];
#pragma unroll
  for (int i = 0; i < 4; ++i)
#pragma unroll
    for (int j = 0; j < 4; ++j) acc[i][j] = f32x4{0.f, 0.f, 0.f, 0.f};
  for (int k0 = 0; k0 < 1024; k0 += 32) {
#pragma unroll
    for (int it = 0; it < 2; ++it) {
      int slot = tid + it * 256;
      int row = slot >> 2, dg = slot & 3;
      *reinterpret_cast<bf16x8*>(&As[row][dg * 8]) =
          *reinterpret_cast<const bf16x8*>(&A[(size_t)(m0 + row) * 1024 + k0 + dg * 8]);
      *reinterpret_cast<bf16x8*>(&Bs[row][dg * 8]) =
          *reinterpret_cast<const bf16x8*>(&BT[(size_t)(n0 + row) * 1024 + k0 + dg * 8]);
    }
    __syncthreads();
    bf16x8 af[4], bfr[4];
#pragma unroll
    for (int i = 0; i < 4; ++i)
      af[i] = *reinterpret_cast<const bf16x8*>(&As[wm * 64 + i * 16 + r16][g4 * 8]);
#pragma unroll
    for (int j = 0; j < 4; ++j)
      bfr[j] = *reinterpret_cast<const bf16x8*>(&Bs[wn * 64 + j * 16 + r16][g4 * 8]);
#pragma unroll
    for (int i = 0; i < 4; ++i)
#pragma unroll
      for (int j = 0; j < 4; ++j)
        acc[i][j] = __builtin_amdgcn_mfma_f32_16x16x32_bf16(af[i], bfr[j], acc[i][j], 0, 0, 0);
    __syncthreads();
  }
#pragma unroll
  for (int i = 0; i < 4; ++i)
#pragma unroll
    for (int j = 0; j < 4; ++j) {
      int row = m0 + wm * 64 + i * 16 + g4 * 4;
      int col = n0 + wn * 64 + j * 16 + r16;
      float bv = bias[col];
#pragma unroll
      for (int q = 0; q < 4; ++q)
        C[(size_t)(row + q) * 3072 + col] = f2bf(acc[i][j][q] + bv);
    }
}

// ---------------- Projection: kproj[b][kk][c] = sum_t Et[kk][t]*k[b][t][c] ----------------
__global__ __launch_bounds__(256) void k_proj(const short* __restrict__ Et,
                                              const short* __restrict__ Ft,
                                              const short* __restrict__ qkv,
                                              short* __restrict__ kp,
                                              short* __restrict__ vp) {
  const int z = blockIdx.z, b = z >> 1, which = z & 1;
  const short* __restrict__ AT = which ? Ft : Et;
  short* __restrict__ outp = which ? vp : kp;
  const int koff = which ? 2048 : 1024;
  const float scale = which ? 1.0f : 0.125f;  // fold 1/sqrt(64) into k_proj
  __shared__ short As[128][40];
  __shared__ short Bs[128][40];
  const int tid = threadIdx.x, lane = tid & 63, w = tid >> 6;
  const int wm = w >> 1, wn = w & 1;
  const int r16 = lane & 15, g4 = lane >> 4;
  const int m0 = blockIdx.x * 128, n0 = blockIdx.y * 128;
  const int cLane = tid & 127, tHalf = tid >> 7;
  f32x4 acc[4][4];
#pragma unroll
  for (int i = 0; i < 4; ++i)
#pragma unroll
    for (int j = 0; j < 4; ++j) acc[i][j] = f32x4{0.f, 0.f, 0.f, 0.f};
  for (int t0 = 0; t0 < 4096; t0 += 32) {
#pragma unroll
    for (int it = 0; it < 2; ++it) {
      int slot = tid + it * 256;
      int row = slot >> 2, dg = slot & 3;
      *reinterpret_cast<bf16x8*>(&As[row][dg * 8]) =
          *reinterpret_cast<const bf16x8*>(&AT[(size_t)(m0 + row) * 4096 + t0 + dg * 8]);
    }
#pragma unroll
    for (int it = 0; it < 16; ++it) {
      int t = tHalf * 16 + it;
      Bs[cLane][t] = qkv[(size_t)(b * 4096 + t0 + t) * 3072 + koff + n0 + cLane];
    }
    __syncthreads();
    bf16x8 af[4], bfr[4];
#pragma unroll
    for (int i = 0; i < 4; ++i)
      af[i] = *reinterpret_cast<const bf16x8*>(&As[wm * 64 + i * 16 + r16][g4 * 8]);
#pragma unroll
    for (int j = 0; j < 4; ++j)
      bfr[j] = *reinterpret_cast<const bf16x8*>(&Bs[wn * 64 + j * 16 + r16][g4 * 8]);
#pragma unroll
    for (int i = 0; i < 4; ++i)
#pragma unroll
      for (int j = 0; j < 4; ++j)
        acc[i][j] = __builtin_amdgcn_mfma_f32_16x16x32_bf16(af[i], bfr[j], acc[i][j], 0, 0, 0);
    __syncthreads();
  }
#pragma unroll
  for (int i = 0; i < 4; ++i)
#pragma unroll
    for (int j = 0; j < 4; ++j) {
      int row = m0 + wm * 64 + i * 16 + g4 * 4;
      int col = n0 + wn * 64 + j * 16 + r16;
#pragma unroll
      for (int q = 0; q < 4; ++q)
        outp[((size_t)(b * 1024) + row + q) * 1024 + col] = f2bf(acc[i][j][q] * scale);
    }
}

// ---------------- Flash attention over 1024 projected slots ----------------
__global__ __launch_bounds__(256) void k_attn(const short* __restrict__ qkv,
                                              const short* __restrict__ kp,
                                              const short* __restrict__ vp,
                                              short* __restrict__ y) {
  struct SMem {
    short Kp[128][72];            // kproj tile [kk][dd]
    short Vt[64][136];            // vproj tile transposed [dd][kk]
    union { short Q[128][72]; short P[4][32][72]; } u;
  };
  __shared__ SMem sm;
  const int tid = threadIdx.x, lane = tid & 63, w = tid >> 6;
  const int r16 = lane & 15, g4 = lane >> 4;
  const int iblk = blockIdx.x;
  const int bh = blockIdx.y, b = bh >> 4, h = bh & 15;
  const int t0 = iblk * 128;

  // stage Q tile (128 x 64)
#pragma unroll
  for (int it = 0; it < 4; ++it) {
    int slot = tid + it * 256;
    int row = slot >> 3, dg = slot & 7;
    *reinterpret_cast<bf16x8*>(&sm.u.Q[row][dg * 8]) =
        *reinterpret_cast<const bf16x8*>(
            &qkv[(size_t)(b * 4096 + t0 + row) * 3072 + h * 64 + dg * 8]);
  }
  __syncthreads();
  bf16x8 aq[2][2];
#pragma unroll
  for (int mi = 0; mi < 2; ++mi)
#pragma unroll
    for (int kd = 0; kd < 2; ++kd)
      aq[mi][kd] = *reinterpret_cast<const bf16x8*>(
          &sm.u.Q[w * 32 + mi * 16 + r16][kd * 32 + g4 * 8]);
  __syncthreads();

  f32x4 o[2][4];
  float mrun[2][4], lrun[2][4];
#pragma unroll
  for (int mi = 0; mi < 2; ++mi) {
#pragma unroll
    for (int q = 0; q < 4; ++q) { mrun[mi][q] = -1e30f; lrun[mi][q] = 0.f; }
#pragma unroll
    for (int nd = 0; nd < 4; ++nd) o[mi][nd] = f32x4{0.f, 0.f, 0.f, 0.f};
  }

  const int ntiles = (iblk + 1 < 8) ? (iblk + 1) : 8;
  for (int jt = 0; jt < ntiles; ++jt) {
    const int kk0 = jt * 128;
    __syncthreads();
#pragma unroll
    for (int it = 0; it < 4; ++it) {
      int slot = tid + it * 256;
      int row = slot >> 3, dg = slot & 7;
      size_t base = (size_t)(b * 1024 + kk0 + row) * 1024 + h * 64 + dg * 8;
      *reinterpret_cast<bf16x8*>(&sm.Kp[row][dg * 8]) =
          *reinterpret_cast<const bf16x8*>(&kp[base]);
      bf16x8 vv = *reinterpret_cast<const bf16x8*>(&vp[base]);
#pragma unroll
      for (int q = 0; q < 8; ++q) sm.Vt[dg * 8 + q][row] = vv[q];
    }
    __syncthreads();

    // S = Q @ Kp^T   (scale already folded into kp)
    f32x4 s[2][8];
#pragma unroll
    for (int mi = 0; mi < 2; ++mi)
#pragma unroll
      for (int n = 0; n < 8; ++n) s[mi][n] = f32x4{0.f, 0.f, 0.f, 0.f};
#pragma unroll
    for (int n = 0; n < 8; ++n)
#pragma unroll
      for (int kd = 0; kd < 2; ++kd) {
        bf16x8 bk = *reinterpret_cast<const bf16x8*>(
            &sm.Kp[n * 16 + r16][kd * 32 + g4 * 8]);
#pragma unroll
        for (int mi = 0; mi < 2; ++mi)
          s[mi][n] = __builtin_amdgcn_mfma_f32_16x16x32_bf16(aq[mi][kd], bk, s[mi][n], 0, 0, 0);
      }

    if (jt == iblk) {  // diagonal tile (only reachable when iblk < 8)
#pragma unroll
      for (int mi = 0; mi < 2; ++mi)
#pragma unroll
        for (int n = 0; n < 8; ++n)
#pragma unroll
          for (int q = 0; q < 4; ++q) {
            int r = w * 32 + mi * 16 + g4 * 4 + q;
            int c = n * 16 + r16;
            if (c > r) s[mi][n][q] = -1e30f;
          }
    }

    // online softmax update
#pragma unroll
    for (int mi = 0; mi < 2; ++mi)
#pragma unroll
      for (int q = 0; q < 4; ++q) {
        float rmax = s[mi][0][q];
#pragma unroll
        for (int n = 1; n < 8; ++n) rmax = fmaxf(rmax, s[mi][n][q]);
#pragma unroll
        for (int off = 1; off < 16; off <<= 1) rmax = fmaxf(rmax, __shfl_xor(rmax, off, 64));
        float mold = mrun[mi][q];
        float newm = fmaxf(mold, rmax);
        float corr = __expf(mold - newm);
        mrun[mi][q] = newm;
        float rsum = 0.f;
#pragma unroll
        for (int n = 0; n < 8; ++n) {
          float pv = __expf(s[mi][n][q] - newm);
          s[mi][n][q] = pv;
          rsum += pv;
        }
#pragma unroll
        for (int off = 1; off < 16; off <<= 1) rsum += __shfl_xor(rsum, off, 64);
        lrun[mi][q] = lrun[mi][q] * corr + rsum;
#pragma unroll
        for (int nd = 0; nd < 4; ++nd) o[mi][nd][q] = o[mi][nd][q] * corr;
      }

    // PV in two 64-col halves through per-wave P buffer
#pragma unroll
    for (int hf = 0; hf < 2; ++hf) {
#pragma unroll
      for (int mi = 0; mi < 2; ++mi)
#pragma unroll
        for (int q = 0; q < 4; ++q)
#pragma unroll
          for (int nn = 0; nn < 4; ++nn)
            sm.u.P[w][mi * 16 + g4 * 4 + q][nn * 16 + r16] = f2bf(s[mi][hf * 4 + nn][q]);
#pragma unroll
      for (int kf = 0; kf < 2; ++kf) {
        bf16x8 ap0 = *reinterpret_cast<const bf16x8*>(&sm.u.P[w][r16][kf * 32 + g4 * 8]);
        bf16x8 ap1 = *reinterpret_cast<const bf16x8*>(&sm.u.P[w][16 + r16][kf * 32 + g4 * 8]);
#pragma unroll
        for (int nd = 0; nd < 4; ++nd) {
          bf16x8 bv = *reinterpret_cast<const bf16x8*>(
              &sm.Vt[nd * 16 + r16][hf * 64 + kf * 32 + g4 * 8]);
          o[0][nd] = __builtin_amdgcn_mfma_f32_16x16x32_bf16(ap0, bv, o[0][nd], 0, 0, 0);
          o[1][nd] = __builtin_amdgcn_mfma_f32_16x16x32_bf16(ap1, bv, o[1][nd], 0, 0, 0);
        }
      }
    }
  }

  // epilogue: y[b][t][h*64+dd] = O / l
#pragma unroll
  for (int mi = 0; mi < 2; ++mi)
#pragma unroll
    for (int q = 0; q < 4; ++q) {
      int tq = t0 + w * 32 + mi * 16 + g4 * 4 + q;
      float inv = 1.0f / lrun[mi][q];
#pragma unroll
      for (int nd = 0; nd < 4; ++nd)
        y[(size_t)(b * 4096 + tq) * 1024 + h * 64 + nd * 16 + r16] = f2bf(o[mi][nd][q] * inv);
    }
}

// ---------------- GEMM2: out = y @ W_proj + b (f32 out) ----------------
__global__ __launch_bounds__(256) void k_gemm_out(const short* __restrict__ A,
                                                  const short* __restrict__ BT,
                                                  const float* __restrict__ bias,
                                                  float* __restrict__ C) {
  __shared__ short As[128][40];
  __shared__ short Bs[128][40];
  const int tid = threadIdx.x, lane = tid & 63, w = tid >> 6;
  const int wm = w >> 1, wn = w & 1;
  const int r16 = lane & 15, g4 = lane >> 4;
  const int m0 = blockIdx.x * 128, n0 = blockIdx.y * 128;
  f32x4 acc[4][4];
#pragma unroll
  for (int i = 0; i < 4; ++i)
#pragma unroll
    for (int j = 0; j < 4; ++j) acc[i][j] = f32x4{0.f, 0.f, 0.f, 0.f};
  for (int k0 = 0; k0 < 1024; k0 += 32) {
#pragma unroll
    for (int it = 0; it < 2; ++it) {
      int slot = tid + it * 256;
      int row = slot >> 2, dg = slot & 3;
      *reinterpret_cast<bf16x8*>(&As[row][dg * 8]) =
          *reinterpret_cast<const bf16x8*>(&A[(size_t)(m0 + row) * 1024 + k0 + dg * 8]);
      *reinterpret_cast<bf16x8*>(&Bs[row][dg * 8]) =
          *reinterpret_cast<const bf16x8*>(&BT[(size_t)(n0 + row) * 1024 + k0 + dg * 8]);
    }
    __syncthreads();
    bf16x8 af[4], bfr[4];
#pragma unroll
    for (int i = 0; i < 4; ++i)
      af[i] = *reinterpret_cast<const bf16x8*>(&As[wm * 64 + i * 16 + r16][g4 * 8]);
#pragma unroll
    for (int j = 0; j < 4; ++j)
      bfr[j] = *reinterpret_cast<const bf16x8*>(&Bs[wn * 64 + j * 16 + r16][g4 * 8]);
#pragma unroll
    for (int i = 0; i < 4; ++i)
#pragma unroll
      for (int j = 0; j < 4; ++j)
        acc[i][j] = __builtin_amdgcn_mfma_f32_16x16x32_bf16(af[i], bfr[j], acc[i][j], 0, 0, 0);
    __syncthreads();
  }
#pragma unroll
  for (int i = 0; i < 4; ++i)
#pragma unroll
    for (int j = 0; j < 4; ++j) {
      int row = m0 + wm * 64 + i * 16 + g4 * 4;
      int col = n0 + wn * 64 + j * 16 + r16;
      float bv = bias[col];
#pragma unroll
      for (int q = 0; q < 4; ++q)
        C[(size_t)(row + q) * 1024 + col] = acc[i][j][q] + bv;
    }
}

extern "C" void kernel_launch(void* const* d_in, const int* in_sizes, int n_in,
                              void* d_out, int out_size, void* d_ws, size_t ws_size,
                              hipStream_t stream) {
  const float* x      = (const float*)d_in[0];
  const float* W_attn = (const float*)d_in[1];
  const float* b_attn = (const float*)d_in[2];
  const float* W_proj = (const float*)d_in[3];
  const float* b_proj = (const float*)d_in[4];
  const float* E      = (const float*)d_in[5];
  const float* F      = (const float*)d_in[6];
  float* out = (float*)d_out;

  char* ws = (char*)d_ws;
  short* xb  = (short*)(ws + 0);          //  32 MB: x bf16            (16384x1024)
  short* WaT = (short*)(ws + 33554432);   //   6 MB: W_attn^T bf16     (3072x1024)
  short* WpT = (short*)(ws + 39845888);   //   2 MB: W_proj^T bf16     (1024x1024)
  short* Et  = (short*)(ws + 41943040);   //   8 MB: E^T bf16          (1024x4096)
  short* Ft  = (short*)(ws + 50331648);   //   8 MB: F^T bf16          (1024x4096)
  short* qkv = (short*)(ws + 58720256);   //  96 MB: qkv bf16          (16384x3072)
  short* kp  = (short*)(ws + 159383552);  //   8 MB: k_proj bf16       (4x1024x1024)
  short* vp  = (short*)(ws + 167772160);  //   8 MB: v_proj bf16       (4x1024x1024)
  short* yb  = (short*)(ws + 176160768);  //  32 MB: attn out bf16     (16384x1024)

  k_convert<<<16384, 256, 0, stream>>>(x, xb, 16777216);
  k_transpose_cvt<<<dim3(96, 32), 256, 0, stream>>>(W_attn, WaT, 1024, 3072);
  k_transpose_cvt<<<dim3(32, 32), 256, 0, stream>>>(W_proj, WpT, 1024, 1024);
  k_transpose_cvt<<<dim3(32, 128), 256, 0, stream>>>(E, Et, 4096, 1024);
  k_transpose_cvt<<<dim3(32, 128), 256, 0, stream>>>(F, Ft, 4096, 1024);

  k_gemm_qkv<<<dim3(128, 24), 256, 0, stream>>>(xb, WaT, b_attn, qkv);
  k_proj<<<dim3(8, 8, 8), 256, 0, stream>>>(Et, Ft, qkv, kp, vp);
  k_attn<<<dim3(32, 64), 256, 0, stream>>>(qkv, kp, vp, yb);
  k_gemm_out<<<dim3(128, 8), 256, 0, stream>>>(yb, WpT, b_proj, out);
}